// Round 4
// baseline (1666.382 us; speedup 1.0000x reference)
//
#include <hip/hip_runtime.h>
#include <hip/hip_bf16.h>
#include <cmath>

// ---- problem constants ----
#define B_     8192
#define INF_   16
#define CS_    6540
#define XCOLS_ 145          // IN_F + LAT + 1
#define MK_    6528         // M*K coeff columns
#define NW_    1088         // M = (IN_F+1)*OUT_F
#define KP_    6656         // CS padded to mult of 128
#define N3P_   6656         // GEMM3 N padded to 26*256

typedef _Float16 f16;
typedef _Float16 f16x8 __attribute__((ext_vector_type(8)));
typedef float    f32x4 __attribute__((ext_vector_type(4)));

#define VMCNT0 do { asm volatile("s_waitcnt vmcnt(0)" ::: "memory"); \
                    __builtin_amdgcn_sched_barrier(0); } while (0)
#define LGKMCNT0 do { asm volatile("s_waitcnt lgkmcnt(0)" ::: "memory"); \
                      __builtin_amdgcn_sched_barrier(0); } while (0)

// ---------------------------------------------------------------------------
__global__ __launch_bounds__(256) void zh_kernel(const float* __restrict__ x,
                                                 f16* __restrict__ zh) {
  int t = blockIdx.x * 256 + threadIdx.x;
  int b = t >> 7, j = t & 127;
  zh[t] = (f16)x[(size_t)b * XCOLS_ + 17 + j];
}

// ---------------------------------------------------------------------------
// transpose-convert fp32 src[K][Ns] -> f16 dst[Np][Kp]  (dst[n][k] = src[k][n])
__global__ __launch_bounds__(256) void tconv_kernel(const float* __restrict__ src,
                                                    f16* __restrict__ dst,
                                                    int Ks, int Ns, int Nlim,
                                                    int Kp, int Np) {
  __shared__ float tile[64][65];
  int k0 = blockIdx.x * 64, n0 = blockIdx.y * 64;
  int tx = threadIdx.x & 63, ty = threadIdx.x >> 6;
#pragma unroll
  for (int i = 0; i < 16; ++i) {
    int r = i * 4 + ty;
    int gk = k0 + r, gn = n0 + tx;
    tile[r][tx] = (gk < Ks && gn < Nlim) ? src[(size_t)gk * Ns + gn] : 0.f;
  }
  __syncthreads();
#pragma unroll
  for (int i = 0; i < 16; ++i) {
    int n = i * 4 + ty;
    int gn = n0 + n, gk = k0 + tx;
    if (gn < Np && gk < Kp) dst[(size_t)gn * Kp + gk] = (f16)tile[tx][n];
  }
}

// ---------------------------------------------------------------------------
// Swizzled LDS tile: phys_byte = logical_byte ^ ((row&7)<<4); rows 64 f16.
__device__ __forceinline__ f16x8 frag_ld(const f16* base, int row, int kb) {
  int off = row * 128 + (kb ^ ((row & 7) << 4));
  return *(const f16x8*)((const char*)base + off);
}

// 256-thread staging (4-wave kernels)
template <int ROWS>
__device__ __forceinline__ void stage_tile(const f16* __restrict__ src, int ld,
                                           int row0, int k0, f16* lds, int tid) {
  constexpr int ISSUES = ROWS / 32;
  const int l = tid & 63, w = tid >> 6;
#pragma unroll
  for (int i = 0; i < ISSUES; ++i) {
    int chunk = i * 4096 + w * 1024;
    int o = chunk + l * 16;
    int r = o >> 7;
    int p = o ^ ((r & 7) << 4);
    int c = (p & 127) >> 1;
    const f16* g = src + (size_t)(row0 + r) * ld + k0 + c;
    __builtin_amdgcn_global_load_lds(
        (const __attribute__((address_space(1))) void*)g,
        (__attribute__((address_space(3))) void*)(lds + (chunk >> 1)),
        16, 0, 0);
  }
}

// 512-thread half-tile staging (128 rows x 64 f16), ld = KP_, 2 loads/thread
__device__ __forceinline__ void stage_half(const f16* __restrict__ src,
                                           int row0, int k0, f16* lds, int tid) {
  const int l = tid & 63, w = tid >> 6;
#pragma unroll
  for (int i = 0; i < 2; ++i) {
    int chunk = i * 8192 + w * 1024;
    int o = chunk + l * 16;
    int r = o >> 7;
    int p = o ^ ((r & 7) << 4);
    int c = (p & 127) >> 1;
    const f16* g = src + (size_t)(row0 + r) * KP_ + k0 + c;
    __builtin_amdgcn_global_load_lds(
        (const __attribute__((address_space(1))) void*)g,
        (__attribute__((address_space(3))) void*)(lds + (chunk >> 1)),
        16, 0, 0);
  }
}

// ---------------------------------------------------------------------------
// NT GEMM (GEMM1/GEMM2): 128x128 tile, 4 waves. out = tanh(acc+bias) f16.
__global__ __launch_bounds__(256) void gemm_nt(
    const f16* __restrict__ A, int lda, const f16* __restrict__ Bt, int ldb,
    const float* __restrict__ bias, int blim, f16* __restrict__ outh, int ldo,
    int Ksteps, int nbn) {
  __shared__ __align__(16) f16 smem[(128 + 128) * 64];
  f16* As = smem;
  f16* Bs = As + 128 * 64;

  const int tid = threadIdx.x;
  const int l = tid & 63, wid = tid >> 6;
  const int wr = wid >> 1, wc = wid & 1;
  const int l15 = l & 15, lg = l >> 4;
  const int bm = blockIdx.x / nbn, bn = blockIdx.x % nbn;
  const int m0 = bm * 128, n0 = bn * 128;

  f32x4 acc[4][4];
#pragma unroll
  for (int mi = 0; mi < 4; ++mi)
#pragma unroll
    for (int ni = 0; ni < 4; ++ni) acc[mi][ni] = (f32x4){0.f, 0.f, 0.f, 0.f};

  for (int ks = 0; ks < Ksteps; ++ks) {
    const int k0 = ks * 64;
    stage_tile<128>(A, lda, m0, k0, As, tid);
    stage_tile<128>(Bt, ldb, n0, k0, Bs, tid);
    __syncthreads();
#pragma unroll
    for (int kk = 0; kk < 64; kk += 32) {
      const int kb = (kk + lg * 8) * 2;
      f16x8 af[4];
#pragma unroll
      for (int mi = 0; mi < 4; ++mi)
        af[mi] = frag_ld(As, wr * 64 + mi * 16 + l15, kb);
#pragma unroll
      for (int ni = 0; ni < 4; ++ni) {
        f16x8 bf = frag_ld(Bs, wc * 64 + ni * 16 + l15, kb);
#pragma unroll
        for (int mi = 0; mi < 4; ++mi)
          acc[mi][ni] = __builtin_amdgcn_mfma_f32_16x16x32_f16(af[mi], bf,
                                                               acc[mi][ni], 0, 0, 0);
      }
    }
    __syncthreads();
  }

#pragma unroll
  for (int ni = 0; ni < 4; ++ni) {
    int col = n0 + wc * 64 + ni * 16 + l15;
    float bv = (col < blim) ? bias[col] : 0.f;
#pragma unroll
    for (int mi = 0; mi < 4; ++mi) {
      int r0 = m0 + wr * 64 + mi * 16 + lg * 4;
#pragma unroll
      for (int j = 0; j < 4; ++j)
        outh[(size_t)(r0 + j) * ldo + col] = (f16)tanhf(acc[mi][ni][j] + bv);
    }
  }
}

// ---------------------------------------------------------------------------
// GEMM3 fused, m201-faithful: 256x256 tile, BK=64, 8 waves (2Mx4N),
// wave-tile 128x64, 4 phases/K-tile of 16 MFMA, half-tile staging spread,
// vmcnt folded after phase-3/7 MFMA, setprio, XCD swizzle.
#define G3_KT 104                     // K-tiles (KP_/64)

#define LOADB(Bc, kb) do { _Pragma("unroll") \
  for (int ni = 0; ni < 4; ++ni) bf[ni] = frag_ld((Bc), wc * 64 + ni * 16 + l15, (kb)); } while (0)
#define LOADA(Ac, kb, mib) do { _Pragma("unroll") \
  for (int j = 0; j < 4; ++j) af[j] = frag_ld((Ac), wr * 128 + ((mib) + j) * 16 + l15, (kb)); } while (0)
#define MFMA16(mib) do { __builtin_amdgcn_s_setprio(1); _Pragma("unroll") \
  for (int j = 0; j < 4; ++j) { _Pragma("unroll") \
    for (int ni = 0; ni < 4; ++ni) \
      acc[(mib) + j][ni] = __builtin_amdgcn_mfma_f32_16x16x32_f16(af[j], bf[ni], acc[(mib) + j][ni], 0, 0, 0); } \
  __builtin_amdgcn_s_setprio(0); } while (0)
#define BAR __builtin_amdgcn_s_barrier()

__global__ __launch_bounds__(512) void gemm3_kernel(
    const f16* __restrict__ A,        // h2: 8192 x KP_
    const f16* __restrict__ Bt,       // W3t: 6656 x KP_ (rows >= 6528 zero)
    const float* __restrict__ bias,   // b3
    const float* __restrict__ vv,     // 8192 x 8
    float* __restrict__ w) {          // 8192 x 1088 (pre-zeroed)
  __shared__ __align__(16) f16 smem[65536];      // 128 KiB
  f16* Ab[2] = {smem, smem + 16384};
  f16* Bb[2] = {smem + 32768, smem + 32768 + 16384};

  const int tid = threadIdx.x;
  const int l = tid & 63, wid = tid >> 6;
  const int wr = wid >> 2, wc = wid & 3;         // 2M x 4N
  const int l15 = l & 15, lg = l >> 4;
  const int wg = (blockIdx.x & 7) * 104 + (blockIdx.x >> 3);   // 832 blocks
  const int bn = wg / 32, bm = wg % 32;          // bm-fast: share B panel in XCD L2
  const int m0 = bm * 256, n0 = bn * 256;
  const int kb0 = lg * 16, kb1 = 64 + lg * 16;

  f32x4 acc[8][4];
#pragma unroll
  for (int mi = 0; mi < 8; ++mi)
#pragma unroll
    for (int ni = 0; ni < 4; ++ni) acc[mi][ni] = (f32x4){0.f, 0.f, 0.f, 0.f};

  // prologue: K-tile 0 into buf0
  stage_half(A, m0, 0, Ab[0], tid);
  stage_half(A, m0 + 128, 0, Ab[0] + 8192, tid);
  stage_half(Bt, n0, 0, Bb[0], tid);
  stage_half(Bt, n0 + 128, 0, Bb[0] + 8192, tid);
  VMCNT0;
  BAR;

  f16x8 af[4], bf[4];
#pragma unroll 1
  for (int it = 0; it < G3_KT / 2; ++it) {
    const int t = 2 * it;
    const int k1 = (t + 1) * 64, k2 = (t + 2) * 64;
    const bool pf = (t + 2 < G3_KT);
    // ---- K-tile t (buf0); stage t+1 -> buf1 at phases 0..2 ----
    // phase 0: kk0, mi0-3
    LOADB(Bb[0], kb0); LOADA(Ab[0], kb0, 0);
    stage_half(A, m0, k1, Ab[1], tid);
    BAR; LGKMCNT0; MFMA16(0); BAR;
    // phase 1: kk0, mi4-7
    LOADA(Ab[0], kb0, 4);
    stage_half(A, m0 + 128, k1, Ab[1] + 8192, tid);
    BAR; LGKMCNT0; MFMA16(4); BAR;
    // phase 2: kk1, mi0-3
    LOADB(Bb[0], kb1); LOADA(Ab[0], kb1, 0);
    stage_half(Bt, n0, k1, Bb[1], tid);
    stage_half(Bt, n0 + 128, k1, Bb[1] + 8192, tid);
    BAR; LGKMCNT0; MFMA16(0); BAR;
    // phase 3: kk1, mi4-7; wait t+1 landed (after MFMA)
    LOADA(Ab[0], kb1, 4);
    BAR; LGKMCNT0; MFMA16(4);
    VMCNT0; BAR;
    // ---- K-tile t+1 (buf1); stage t+2 -> buf0 at phases 4..6 ----
    // phase 4
    LOADB(Bb[1], kb0); LOADA(Ab[1], kb0, 0);
    if (pf) stage_half(A, m0, k2, Ab[0], tid);
    BAR; LGKMCNT0; MFMA16(0); BAR;
    // phase 5
    LOADA(Ab[1], kb0, 4);
    if (pf) stage_half(A, m0 + 128, k2, Ab[0] + 8192, tid);
    BAR; LGKMCNT0; MFMA16(4); BAR;
    // phase 6
    LOADB(Bb[1], kb1); LOADA(Ab[1], kb1, 0);
    if (pf) {
      stage_half(Bt, n0, k2, Bb[0], tid);
      stage_half(Bt, n0 + 128, k2, Bb[0] + 8192, tid);
    }
    BAR; LGKMCNT0; MFMA16(0); BAR;
    // phase 7; wait t+2 landed (after MFMA)
    LOADA(Ab[1], kb1, 4);
    BAR; LGKMCNT0; MFMA16(4);
    VMCNT0; BAR;
  }

  // ---- fused epilogue: 4 quarters of 64 rows; group-6 contraction ----
  float* Cl = (float*)smem;                      // [64][257] fp32
  const int gFirst = n0 / 6;
  int gEnd = (n0 + 255) / 6; if (gEnd > 1087) gEnd = 1087;
  const int ng = gEnd - gFirst + 1;
#pragma unroll 1
  for (int q = 0; q < 4; ++q) {
    __syncthreads();
    if (wr == (q >> 1)) {
      const int mib = (q & 1) * 4;
#pragma unroll
      for (int mi2 = 0; mi2 < 4; ++mi2) {
#pragma unroll
        for (int ni = 0; ni < 4; ++ni) {
          int cl = wc * 64 + ni * 16 + l15;
          int gc = n0 + cl;
          float bv = (gc < MK_) ? bias[gc] : 0.f;
#pragma unroll
          for (int j = 0; j < 4; ++j)
            Cl[(mi2 * 16 + lg * 4 + j) * 257 + cl] = acc[mib + mi2][ni][j] + bv;
        }
      }
    }
    __syncthreads();
    for (int idx = tid; idx < 64 * ng; idx += 512) {
      int r = idx / ng, jg = idx - r * ng;
      int g = gFirst + jg;
      int base = 6 * g - n0;
      int lo = base > 0 ? base : 0;
      int hi = base + 6 < 256 ? base + 6 : 256;
      const float* vr = vv + (size_t)(m0 + q * 64 + r) * 8;
      float s = 0.f;
      for (int c = lo; c < hi; ++c) s += Cl[r * 257 + c] * vr[c - base];
      float* dst = &w[(size_t)(m0 + q * 64 + r) * NW_ + g];
      if (base >= 0 && base + 6 <= 256) *dst = s;
      else atomicAdd(dst, s);
    }
  }
}

// ---------------------------------------------------------------------------
// dil/shift strip (12 x KP_ f16), then v.
__global__ __launch_bounds__(256) void sv_kernel(const f16* __restrict__ h2,
                                                 const f16* __restrict__ dil12,
                                                 const float* __restrict__ b3,
                                                 const float* __restrict__ x,
                                                 float* __restrict__ vv) {
  __shared__ float red[12][4];
  int b = blockIdx.x, tid = threadIdx.x;
  int lane = tid & 63, wid = tid >> 6;
  float p[12];
#pragma unroll
  for (int j = 0; j < 12; ++j) p[j] = 0.f;
  for (int c = tid; c < KP_ / 8; c += 256) {
    f16x8 hv = *(const f16x8*)(h2 + (size_t)b * KP_ + c * 8);
#pragma unroll
    for (int j = 0; j < 12; ++j) {
      f16x8 wv = *(const f16x8*)(dil12 + (size_t)j * KP_ + c * 8);
      float s = 0.f;
#pragma unroll
      for (int e = 0; e < 8; ++e) s += (float)hv[e] * (float)wv[e];
      p[j] += s;
    }
  }
#pragma unroll
  for (int j = 0; j < 12; ++j) {
    float v = p[j];
    for (int off = 32; off; off >>= 1) v += __shfl_down(v, off, 64);
    if (lane == 0) red[j][wid] = v;
  }
  __syncthreads();
  if (tid < 6) {
    int j = tid;
    float dil = red[j][0] + red[j][1] + red[j][2] + red[j][3] + b3[MK_ + j];
    float sh  = red[6 + j][0] + red[6 + j][1] + red[6 + j][2] + red[6 + j][3] + b3[MK_ + 6 + j];
    float s = x[(size_t)(B_ - 1) * XCOLS_ + INF_];
    float sv = s * dil + sh;
    vv[(size_t)b * 8 + j] = (j < 3) ? cosf(sv * (float)j) : sinf(sv * (float)(j - 3));
  }
}

// ---------------------------------------------------------------------------
__global__ __launch_bounds__(256) void out_kernel(const float* __restrict__ x,
                                                  const float* __restrict__ w,
                                                  float* __restrict__ out) {
  int wid = threadIdx.x >> 6, lane = threadIdx.x & 63;
  int b = blockIdx.x * 4 + wid;
  const float* wr = w + (size_t)b * NW_;
  const float* xr = x + (size_t)b * XCOLS_;
  float acc = wr[1024 + lane];
#pragma unroll
  for (int i = 0; i < 16; ++i) acc += xr[i] * wr[i * 64 + lane];
  out[(size_t)b * 64 + lane] = acc;
}

// ---------------------------------------------------------------------------
extern "C" void kernel_launch(void* const* d_in, const int* in_sizes, int n_in,
                              void* d_out, int out_size, void* d_ws, size_t ws_size,
                              hipStream_t stream) {
  const float* x  = (const float*)d_in[0];
  const float* W1 = (const float*)d_in[1];
  const float* b1 = (const float*)d_in[2];
  const float* W2 = (const float*)d_in[3];
  const float* b2 = (const float*)d_in[4];
  const float* W3 = (const float*)d_in[5];
  const float* b3 = (const float*)d_in[6];
  float* out = (float*)d_out;

  char* ws = (char*)d_ws;
  f16*   zh  = (f16*)(ws);                        //  2,097,152 B (reused as dil12)
  f16*   W1t = (f16*)(ws + 2097152);              //    262,144 B
  f16*   W2t = (f16*)(ws + 2359296);              // 13,631,488 B  (6656 x 1024)
  f16*   W3t = (f16*)(ws + 15990784);             // 88,604,672 B  (6656 x 6656)
  f16*   h1  = (f16*)(ws + 104595456);            // 16,777,216 B  (8192 x 1024)
  f16*   h2  = (f16*)(ws + 121372672);            //109,051,904 B  (8192 x 6656)
  float* vv  = (float*)(ws + 230424576);          //    262,144 B
  float* w   = (float*)(ws + 230686720);          // 35,651,584 B  (8192 x 1088)
  // total 266,338,304 B
  f16*   dil12 = zh;

  hipMemsetAsync(w, 0, (size_t)B_ * NW_ * 4, stream);   // epilogue atomics need 0

  zh_kernel<<<4096, 256, 0, stream>>>(x, zh);
  tconv_kernel<<<dim3(2, 16),    256, 0, stream>>>(W1, W1t, 128,  1024, 1024, 128,  1024);
  tconv_kernel<<<dim3(16, 104),  256, 0, stream>>>(W2, W2t, 1024, CS_,  CS_,  1024, KP_);
  tconv_kernel<<<dim3(104, 104), 256, 0, stream>>>(W3, W3t, CS_,  CS_,  MK_,  KP_,  N3P_);

  // GEMM1: h1 = tanh(zh @ W1 + b1)
  gemm_nt<<<(1024 / 128) * (B_ / 128), 256, 0, stream>>>(
      zh, 128, W1t, 128, b1, 1024, h1, 1024, 2, 1024 / 128);
  // dil/shift strip into dead zh region
  tconv_kernel<<<dim3(104, 1),   256, 0, stream>>>(W3 + MK_, dil12, CS_, CS_, 12, KP_, 12);
  // GEMM2: h2 = tanh(h1 @ W2 + b2)
  gemm_nt<<<(KP_ / 128) * (B_ / 128), 256, 0, stream>>>(
      h1, 1024, W2t, 1024, b2, CS_, h2, KP_, 16, KP_ / 128);
  // dilation/shift + v
  sv_kernel<<<B_, 256, 0, stream>>>(h2, dil12, b3, x, vv);
  // GEMM3 fused (256x256 8-phase)
  gemm3_kernel<<<(B_ / 256) * (N3P_ / 256), 512, 0, stream>>>(h2, W3t, b3, vv, w);
  // final einsum
  out_kernel<<<B_ / 4, 256, 0, stream>>>(x, w, out);
}